// Round 1
// baseline (686.847 us; speedup 1.0000x reference)
//
#include <hip/hip_runtime.h>
#include <hip/hip_bf16.h>

// GAT: N=50000 nodes, DIN=128, HID=128 (4 heads x 32), DOUT=16, E=800000 (+N self loops)

static inline int divup(int a, int b){ return (a + b - 1) / b; }

// ---------------- CSR build ----------------

__global__ __launch_bounds__(256) void count_deg_kernel(const int* __restrict__ dst,
                                                        int* __restrict__ deg, int E, int Et){
    int e = blockIdx.x * 256 + threadIdx.x;
    if (e >= Et) return;
    int d = (e < E) ? dst[e] : (e - E);   // self loop for e >= E
    atomicAdd(&deg[d], 1);
}

__global__ __launch_bounds__(1024) void scan_kernel(const int* __restrict__ deg,
                                                    int* __restrict__ rowptr, int n, int total){
    __shared__ int sums[1024];
    int t = threadIdx.x;
    int C = (n + 1023) >> 10;
    int b = t * C;
    int e = b + C; if (e > n) e = n;
    int s = 0;
    for (int i = b; i < e; ++i) s += deg[i];
    sums[t] = s;
    __syncthreads();
    for (int off = 1; off < 1024; off <<= 1){
        int v = (t >= off) ? sums[t - off] : 0;
        __syncthreads();
        sums[t] += v;
        __syncthreads();
    }
    int run = sums[t] - s;  // exclusive prefix of this chunk
    for (int i = b; i < e; ++i){ rowptr[i] = run; run += deg[i]; }
    if (t == 0) rowptr[n] = total;
}

__global__ __launch_bounds__(256) void fill_csr_kernel(const int* __restrict__ src,
                                                       const int* __restrict__ dst,
                                                       const int* __restrict__ rowptr,
                                                       int* __restrict__ cursor,
                                                       int* __restrict__ csr_src, int E, int Et){
    int e = blockIdx.x * 256 + threadIdx.x;
    if (e >= Et) return;
    int d, s;
    if (e < E){ d = dst[e]; s = src[e]; } else { d = e - E; s = d; }
    int pos = atomicAdd(&cursor[d], 1);
    csr_src[rowptr[d] + pos] = s;
}

// ---------------- GEMM: [n,128] x [128,128] -> [n,128] ----------------
// block: 256 threads, 32 nodes; W staged in 64-col halves (32KB), X tile 32x132 (16.5KB)

__global__ __launch_bounds__(256) void gemm128_kernel(const float* __restrict__ X,
                                                      const float* __restrict__ W,
                                                      float* __restrict__ H, int n){
    __shared__ float Xs[32][132];
    __shared__ float Ws[128][64];
    int tid = threadIdx.x;
    int nb = blockIdx.x * 32;

    for (int i = tid; i < 32 * 128; i += 256){
        int r = i >> 7, c = i & 127;
        int node = nb + r;
        Xs[r][c] = (node < n) ? X[(size_t)node * 128 + c] : 0.f;
    }

    int tx = tid & 15, ty = tid >> 4;        // tx: 16 col groups of 4, ty: 16 node pairs
    int n0 = nb + 2 * ty, n1 = n0 + 1;

    for (int half = 0; half < 2; ++half){
        __syncthreads();
        for (int i = tid; i < 128 * 64; i += 256){
            int k = i >> 6, jl = i & 63;
            Ws[k][jl] = W[(size_t)k * 128 + half * 64 + jl];
        }
        __syncthreads();

        float a00=0,a01=0,a02=0,a03=0, a10=0,a11=0,a12=0,a13=0;
        const float* xr0 = &Xs[2 * ty][0];
        const float* xr1 = &Xs[2 * ty + 1][0];
        for (int k = 0; k < 128; k += 4){
            float4 xa = *(const float4*)(xr0 + k);
            float4 xb = *(const float4*)(xr1 + k);
            #pragma unroll
            for (int kk = 0; kk < 4; ++kk){
                float4 w = *(const float4*)&Ws[k + kk][tx * 4];
                float xav = (kk == 0) ? xa.x : (kk == 1) ? xa.y : (kk == 2) ? xa.z : xa.w;
                float xbv = (kk == 0) ? xb.x : (kk == 1) ? xb.y : (kk == 2) ? xb.z : xb.w;
                a00 += xav * w.x; a01 += xav * w.y; a02 += xav * w.z; a03 += xav * w.w;
                a10 += xbv * w.x; a11 += xbv * w.y; a12 += xbv * w.z; a13 += xbv * w.w;
            }
        }
        int j = half * 64 + tx * 4;
        if (n0 < n){ float4 v = {a00,a01,a02,a03}; *(float4*)&H[(size_t)n0 * 128 + j] = v; }
        if (n1 < n){ float4 v = {a10,a11,a12,a13}; *(float4*)&H[(size_t)n1 * 128 + j] = v; }
    }
}

// ---------------- attention logits: als/ald [n,4] ----------------

__global__ __launch_bounds__(256) void al128_kernel(const float* __restrict__ H,
                                                    const float* __restrict__ as_,
                                                    const float* __restrict__ ad_,
                                                    float* __restrict__ als,
                                                    float* __restrict__ ald, int n){
    int gid = blockIdx.x * 256 + threadIdx.x;
    if (gid >= n * 4) return;
    int h = gid & 3, node = gid >> 2;
    const float4* hr  = (const float4*)(H + (size_t)node * 128 + h * 32);
    const float4* asr = (const float4*)(as_ + h * 32);
    const float4* adr = (const float4*)(ad_ + h * 32);
    float ss = 0.f, sd = 0.f;
    #pragma unroll
    for (int i = 0; i < 8; ++i){
        float4 hv = hr[i], av = asr[i], dv = adr[i];
        ss += hv.x*av.x + hv.y*av.y + hv.z*av.z + hv.w*av.w;
        sd += hv.x*dv.x + hv.y*dv.y + hv.z*dv.z + hv.w*dv.w;
    }
    als[gid] = ss; ald[gid] = sd;
}

// ---------------- aggregation (128 ch, 4 heads): one wave per node ----------------

__global__ __launch_bounds__(256) void aggregate128_kernel(const float* __restrict__ H,
                                                           const float* __restrict__ als,
                                                           const float* __restrict__ ald,
                                                           const int* __restrict__ rowptr,
                                                           const int* __restrict__ csr_src,
                                                           const float* __restrict__ bias,
                                                           float* __restrict__ out,
                                                           int n, int do_elu){
    int node = blockIdx.x * 4 + (threadIdx.x >> 6);
    int lane = threadIdx.x & 63;
    if (node >= n) return;
    int start = rowptr[node], end = rowptr[node + 1];
    float4 ad4 = *(const float4*)(ald + (size_t)node * 4);

    // pass 1: per-head max (lane-parallel over edges, butterfly reduce)
    float mx0 = -1e30f, mx1 = -1e30f, mx2 = -1e30f, mx3 = -1e30f;
    for (int i = start + lane; i < end; i += 64){
        int s = csr_src[i];
        float4 as4 = *(const float4*)(als + (size_t)s * 4);
        float e0 = as4.x + ad4.x; e0 = e0 > 0.f ? e0 : 0.2f * e0;
        float e1 = as4.y + ad4.y; e1 = e1 > 0.f ? e1 : 0.2f * e1;
        float e2 = as4.z + ad4.z; e2 = e2 > 0.f ? e2 : 0.2f * e2;
        float e3 = as4.w + ad4.w; e3 = e3 > 0.f ? e3 : 0.2f * e3;
        mx0 = fmaxf(mx0, e0); mx1 = fmaxf(mx1, e1);
        mx2 = fmaxf(mx2, e2); mx3 = fmaxf(mx3, e3);
    }
    for (int off = 32; off > 0; off >>= 1){
        mx0 = fmaxf(mx0, __shfl_xor(mx0, off));
        mx1 = fmaxf(mx1, __shfl_xor(mx1, off));
        mx2 = fmaxf(mx2, __shfl_xor(mx2, off));
        mx3 = fmaxf(mx3, __shfl_xor(mx3, off));
    }

    int h = lane >> 4;                       // lane's head (2 channels per lane)
    float m_h  = (h == 0) ? mx0  : (h == 1) ? mx1  : (h == 2) ? mx2  : mx3;
    float ad_h = (h == 0) ? ad4.x : (h == 1) ? ad4.y : (h == 2) ? ad4.z : ad4.w;

    // pass 2: fused exp/denominator/weighted-sum, all lanes walk every edge
    float den = 0.f, accx = 0.f, accy = 0.f;
    int col = lane * 2;
    for (int i = start; i < end; ++i){
        int s = csr_src[i];
        float e = als[(size_t)s * 4 + h] + ad_h;
        e = e > 0.f ? e : 0.2f * e;
        float ee = __expf(e - m_h);
        den += ee;
        float2 hv = *(const float2*)(H + (size_t)s * 128 + col);
        accx += ee * hv.x; accy += ee * hv.y;
    }
    float inv = 1.f / (den + 1e-16f);
    float2 bv = *(const float2*)(bias + col);
    float vx = accx * inv + bv.x;
    float vy = accy * inv + bv.y;
    if (do_elu){
        vx = vx > 0.f ? vx : __expf(vx) - 1.f;
        vy = vy > 0.f ? vy : __expf(vy) - 1.f;
    }
    float2 o = {vx, vy};
    *(float2*)(out + (size_t)node * 128 + col) = o;
}

// ---------------- layer 4: [n,128] x [128,16], heads=1 ----------------

__global__ __launch_bounds__(256) void gemm16_kernel(const float* __restrict__ X,
                                                     const float* __restrict__ W,
                                                     float* __restrict__ H4, int n){
    __shared__ float Ws[128 * 16];
    int tid = threadIdx.x;
    for (int i = tid; i < 2048; i += 256) Ws[i] = W[i];
    __syncthreads();
    int gid = blockIdx.x * 256 + tid;
    if (gid >= n * 16) return;
    int j = gid & 15, node = gid >> 4;
    const float4* xr = (const float4*)(X + (size_t)node * 128);
    float s = 0.f;
    #pragma unroll 8
    for (int k4 = 0; k4 < 32; ++k4){
        float4 xv = xr[k4];
        s += xv.x * Ws[(k4*4+0)*16 + j] + xv.y * Ws[(k4*4+1)*16 + j]
           + xv.z * Ws[(k4*4+2)*16 + j] + xv.w * Ws[(k4*4+3)*16 + j];
    }
    H4[gid] = s;
}

__global__ __launch_bounds__(256) void al16_kernel(const float* __restrict__ H4,
                                                   const float* __restrict__ as2,
                                                   const float* __restrict__ ad2,
                                                   float* __restrict__ als4,
                                                   float* __restrict__ ald4, int n){
    int node = blockIdx.x * 256 + threadIdx.x;
    if (node >= n) return;
    const float4* hr = (const float4*)(H4 + (size_t)node * 16);
    const float4* asr = (const float4*)as2;
    const float4* adr = (const float4*)ad2;
    float ss = 0.f, sd = 0.f;
    #pragma unroll
    for (int i = 0; i < 4; ++i){
        float4 hv = hr[i], av = asr[i], dv = adr[i];
        ss += hv.x*av.x + hv.y*av.y + hv.z*av.z + hv.w*av.w;
        sd += hv.x*dv.x + hv.y*dv.y + hv.z*dv.z + hv.w*dv.w;
    }
    als4[node] = ss; ald4[node] = sd;
}

__global__ __launch_bounds__(256) void aggregate16_kernel(const float* __restrict__ H4,
                                                          const float* __restrict__ als4,
                                                          const float* __restrict__ ald4,
                                                          const int* __restrict__ rowptr,
                                                          const int* __restrict__ csr_src,
                                                          const float* __restrict__ bias,
                                                          float* __restrict__ out, int n){
    int gid = blockIdx.x * 256 + threadIdx.x;
    if (gid >= n * 16) return;
    int c = gid & 15, node = gid >> 4;
    int start = rowptr[node], end = rowptr[node + 1];
    float adn = ald4[node];
    float m = -1e30f;
    for (int i = start; i < end; ++i){
        int s = csr_src[i];
        float e = als4[s] + adn;
        e = e > 0.f ? e : 0.2f * e;
        m = fmaxf(m, e);
    }
    float den = 0.f, acc = 0.f;
    for (int i = start; i < end; ++i){
        int s = csr_src[i];
        float e = als4[s] + adn;
        e = e > 0.f ? e : 0.2f * e;
        float ee = __expf(e - m);
        den += ee;
        acc += ee * H4[(size_t)s * 16 + c];
    }
    out[gid] = acc / (den + 1e-16f) + bias[c];
}

// ---------------- launcher ----------------

extern "C" void kernel_launch(void* const* d_in, const int* in_sizes, int n_in,
                              void* d_out, int out_size, void* d_ws, size_t ws_size,
                              hipStream_t stream) {
    const float* x   = (const float*)d_in[0];
    const int*   ei  = (const int*)d_in[1];
    const float* W1  = (const float*)d_in[3];
    const float* as1 = (const float*)d_in[4];
    const float* ad1 = (const float*)d_in[5];
    const float* b1  = (const float*)d_in[6];
    const float* Wh  = (const float*)d_in[7];
    const float* ash = (const float*)d_in[8];
    const float* adh = (const float*)d_in[9];
    const float* bh  = (const float*)d_in[10];
    const float* W2  = (const float*)d_in[11];
    const float* as2 = (const float*)d_in[12];
    const float* ad2 = (const float*)d_in[13];
    const float* b2  = (const float*)d_in[14];

    int N = in_sizes[0] / 128;
    int E = in_sizes[1] / 2;
    int Et = E + N;
    const int* srcA = ei;
    const int* dstA = ei + E;

    char* ws = (char*)d_ws;
    size_t off = 0;
    auto alloc = [&](size_t bytes) -> void* {
        void* p = ws + off;
        off = (off + bytes + 255) & ~(size_t)255;
        return p;
    };
    int* degcur  = (int*)alloc((size_t)2 * N * 4);    // deg + cursor, zeroed together
    int* deg     = degcur;
    int* cursor  = degcur + N;
    int* rowptr  = (int*)alloc((size_t)(N + 1) * 4);
    int* csr_src = (int*)alloc((size_t)Et * 4);
    float* xbuf  = (float*)alloc((size_t)N * 128 * 4);
    float* hfeat = (float*)alloc((size_t)N * 128 * 4);
    float* als   = (float*)alloc((size_t)N * 4 * 4);
    float* ald   = (float*)alloc((size_t)N * 4 * 4);
    float* h4    = (float*)alloc((size_t)N * 16 * 4);
    float* als4  = (float*)alloc((size_t)N * 4);
    float* ald4  = (float*)alloc((size_t)N * 4);

    hipMemsetAsync(degcur, 0, (size_t)2 * N * 4, stream);
    count_deg_kernel<<<divup(Et, 256), 256, 0, stream>>>(dstA, deg, E, Et);
    scan_kernel<<<1, 1024, 0, stream>>>(deg, rowptr, N, Et);
    fill_csr_kernel<<<divup(Et, 256), 256, 0, stream>>>(srcA, dstA, rowptr, cursor, csr_src, E, Et);

    float* out = (float*)d_out;

    // layer 1
    gemm128_kernel<<<divup(N, 32), 256, 0, stream>>>(x, W1, hfeat, N);
    al128_kernel<<<divup(N * 4, 256), 256, 0, stream>>>(hfeat, as1, ad1, als, ald, N);
    aggregate128_kernel<<<divup(N, 4), 256, 0, stream>>>(hfeat, als, ald, rowptr, csr_src, b1, xbuf, N, 1);

    // hidden layers 2,3
    for (int l = 0; l < 2; ++l){
        gemm128_kernel<<<divup(N, 32), 256, 0, stream>>>(xbuf, Wh + (size_t)l * 128 * 128, hfeat, N);
        al128_kernel<<<divup(N * 4, 256), 256, 0, stream>>>(hfeat, ash + l * 128, adh + l * 128, als, ald, N);
        aggregate128_kernel<<<divup(N, 4), 256, 0, stream>>>(hfeat, als, ald, rowptr, csr_src, bh + l * 128, xbuf, N, 1);
    }

    // layer 4 (heads=1, 16 out)
    gemm16_kernel<<<divup(N * 16, 256), 256, 0, stream>>>(xbuf, W2, h4, N);
    al16_kernel<<<divup(N, 256), 256, 0, stream>>>(h4, as2, ad2, als4, ald4, N);
    aggregate16_kernel<<<divup(N * 16, 256), 256, 0, stream>>>(h4, als4, ald4, rowptr, csr_src, b2, out, N);
}

// Round 3
// 568.255 us; speedup vs baseline: 1.2087x; 1.2087x over previous
//
#include <hip/hip_runtime.h>
#include <hip/hip_bf16.h>

// GAT: N=50000 nodes, DIN=128, HID=128 (4 heads x 32), DOUT=16, E=800000 (+N self loops)

static inline int divup(int a, int b){ return (a + b - 1) / b; }

// ---------------- CSR build ----------------

__global__ __launch_bounds__(256) void count_deg_kernel(const int* __restrict__ dst,
                                                        int* __restrict__ deg, int E, int Et){
    int e = blockIdx.x * 256 + threadIdx.x;
    if (e >= Et) return;
    int d = (e < E) ? dst[e] : (e - E);   // self loop for e >= E
    atomicAdd(&deg[d], 1);
}

__global__ __launch_bounds__(1024) void scan_kernel(const int* __restrict__ deg,
                                                    int* __restrict__ rowptr, int n, int total){
    __shared__ int sums[1024];
    int t = threadIdx.x;
    int C = (n + 1023) >> 10;
    int b = t * C;
    int e = b + C; if (e > n) e = n;
    int s = 0;
    for (int i = b; i < e; ++i) s += deg[i];
    sums[t] = s;
    __syncthreads();
    for (int off = 1; off < 1024; off <<= 1){
        int v = (t >= off) ? sums[t - off] : 0;
        __syncthreads();
        sums[t] += v;
        __syncthreads();
    }
    int run = sums[t] - s;  // exclusive prefix of this chunk
    for (int i = b; i < e; ++i){ rowptr[i] = run; run += deg[i]; }
    if (t == 0) rowptr[n] = total;
}

__global__ __launch_bounds__(256) void fill_csr_kernel(const int* __restrict__ src,
                                                       const int* __restrict__ dst,
                                                       const int* __restrict__ rowptr,
                                                       int* __restrict__ cursor,
                                                       int* __restrict__ csr_src, int E, int Et){
    int e = blockIdx.x * 256 + threadIdx.x;
    if (e >= Et) return;
    int d, s;
    if (e < E){ d = dst[e]; s = src[e]; } else { d = e - E; s = d; }
    int pos = atomicAdd(&cursor[d], 1);
    csr_src[rowptr[d] + pos] = s;
}

// ---------------- GEMM: [n,128] x [128,128] -> [n,128] ----------------

__global__ __launch_bounds__(256) void gemm128_kernel(const float* __restrict__ X,
                                                      const float* __restrict__ W,
                                                      float* __restrict__ H, int n){
    __shared__ float Xs[32][132];
    __shared__ float Ws[128][64];
    int tid = threadIdx.x;
    int nb = blockIdx.x * 32;

    for (int i = tid; i < 32 * 128; i += 256){
        int r = i >> 7, c = i & 127;
        int node = nb + r;
        Xs[r][c] = (node < n) ? X[(size_t)node * 128 + c] : 0.f;
    }

    int tx = tid & 15, ty = tid >> 4;
    int n0 = nb + 2 * ty, n1 = n0 + 1;

    for (int half = 0; half < 2; ++half){
        __syncthreads();
        for (int i = tid; i < 128 * 64; i += 256){
            int k = i >> 6, jl = i & 63;
            Ws[k][jl] = W[(size_t)k * 128 + half * 64 + jl];
        }
        __syncthreads();

        float a00=0,a01=0,a02=0,a03=0, a10=0,a11=0,a12=0,a13=0;
        const float* xr0 = &Xs[2 * ty][0];
        const float* xr1 = &Xs[2 * ty + 1][0];
        for (int k = 0; k < 128; k += 4){
            float4 xa = *(const float4*)(xr0 + k);
            float4 xb = *(const float4*)(xr1 + k);
            #pragma unroll
            for (int kk = 0; kk < 4; ++kk){
                float4 w = *(const float4*)&Ws[k + kk][tx * 4];
                float xav = (kk == 0) ? xa.x : (kk == 1) ? xa.y : (kk == 2) ? xa.z : xa.w;
                float xbv = (kk == 0) ? xb.x : (kk == 1) ? xb.y : (kk == 2) ? xb.z : xb.w;
                a00 += xav * w.x; a01 += xav * w.y; a02 += xav * w.z; a03 += xav * w.w;
                a10 += xbv * w.x; a11 += xbv * w.y; a12 += xbv * w.z; a13 += xbv * w.w;
            }
        }
        int j = half * 64 + tx * 4;
        if (n0 < n){ float4 v = {a00,a01,a02,a03}; *(float4*)&H[(size_t)n0 * 128 + j] = v; }
        if (n1 < n){ float4 v = {a10,a11,a12,a13}; *(float4*)&H[(size_t)n1 * 128 + j] = v; }
    }
}

// ---------------- attention logits: als/ald [n,4] ----------------

__global__ __launch_bounds__(256) void al128_kernel(const float* __restrict__ H,
                                                    const float* __restrict__ as_,
                                                    const float* __restrict__ ad_,
                                                    float* __restrict__ als,
                                                    float* __restrict__ ald, int n){
    int gid = blockIdx.x * 256 + threadIdx.x;
    if (gid >= n * 4) return;
    int h = gid & 3, node = gid >> 2;
    const float4* hr  = (const float4*)(H + (size_t)node * 128 + h * 32);
    const float4* asr = (const float4*)(as_ + h * 32);
    const float4* adr = (const float4*)(ad_ + h * 32);
    float ss = 0.f, sd = 0.f;
    #pragma unroll
    for (int i = 0; i < 8; ++i){
        float4 hv = hr[i], av = asr[i], dv = adr[i];
        ss += hv.x*av.x + hv.y*av.y + hv.z*av.z + hv.w*av.w;
        sd += hv.x*dv.x + hv.y*dv.y + hv.z*dv.z + hv.w*dv.w;
    }
    als[gid] = ss; ald[gid] = sd;
}

// ---------------- aggregation (128 ch, 4 heads): one wave per node ----------------
// pass1: lane-parallel max; pass2: lane-parallel denom; pass3: 4 edge-groups x 16 ch-lanes

__global__ __launch_bounds__(256) void aggregate128_kernel(const float* __restrict__ H,
                                                           const float* __restrict__ als,
                                                           const float* __restrict__ ald,
                                                           const int* __restrict__ rowptr,
                                                           const int* __restrict__ csr_src,
                                                           const float* __restrict__ bias,
                                                           float* __restrict__ out,
                                                           int n, int do_elu){
    int node = blockIdx.x * 4 + (threadIdx.x >> 6);
    int lane = threadIdx.x & 63;
    if (node >= n) return;
    int start = rowptr[node], end = rowptr[node + 1];
    float4 ad4 = *(const float4*)(ald + (size_t)node * 4);

    // pass 1: per-head max (lane-parallel, typically 1 iteration since deg < 64)
    float mx0 = -1e30f, mx1 = -1e30f, mx2 = -1e30f, mx3 = -1e30f;
    for (int i = start + lane; i < end; i += 64){
        int s = csr_src[i];
        float4 a = *(const float4*)(als + (size_t)s * 4);
        float e0 = a.x + ad4.x; e0 = e0 > 0.f ? e0 : 0.2f * e0;
        float e1 = a.y + ad4.y; e1 = e1 > 0.f ? e1 : 0.2f * e1;
        float e2 = a.z + ad4.z; e2 = e2 > 0.f ? e2 : 0.2f * e2;
        float e3 = a.w + ad4.w; e3 = e3 > 0.f ? e3 : 0.2f * e3;
        mx0 = fmaxf(mx0, e0); mx1 = fmaxf(mx1, e1);
        mx2 = fmaxf(mx2, e2); mx3 = fmaxf(mx3, e3);
    }
    #pragma unroll
    for (int off = 32; off > 0; off >>= 1){
        mx0 = fmaxf(mx0, __shfl_xor(mx0, off));
        mx1 = fmaxf(mx1, __shfl_xor(mx1, off));
        mx2 = fmaxf(mx2, __shfl_xor(mx2, off));
        mx3 = fmaxf(mx3, __shfl_xor(mx3, off));
    }

    // pass 2: per-head denominator (lane-parallel)
    float d0 = 0.f, d1 = 0.f, d2 = 0.f, d3 = 0.f;
    for (int i = start + lane; i < end; i += 64){
        int s = csr_src[i];
        float4 a = *(const float4*)(als + (size_t)s * 4);
        float e0 = a.x + ad4.x; e0 = e0 > 0.f ? e0 : 0.2f * e0;
        float e1 = a.y + ad4.y; e1 = e1 > 0.f ? e1 : 0.2f * e1;
        float e2 = a.z + ad4.z; e2 = e2 > 0.f ? e2 : 0.2f * e2;
        float e3 = a.w + ad4.w; e3 = e3 > 0.f ? e3 : 0.2f * e3;
        d0 += __expf(e0 - mx0); d1 += __expf(e1 - mx1);
        d2 += __expf(e2 - mx2); d3 += __expf(e3 - mx3);
    }
    #pragma unroll
    for (int off = 32; off > 0; off >>= 1){
        d0 += __shfl_xor(d0, off); d1 += __shfl_xor(d1, off);
        d2 += __shfl_xor(d2, off); d3 += __shfl_xor(d3, off);
    }

    // pass 3: numerator — 4 edge groups x 16 channel lanes (8 ch each), unroll 2
    int eg = lane >> 4, cl = lane & 15;
    int h = cl >> 2;
    float m_h   = (h == 0) ? mx0  : (h == 1) ? mx1  : (h == 2) ? mx2  : mx3;
    float ad_h  = (h == 0) ? ad4.x : (h == 1) ? ad4.y : (h == 2) ? ad4.z : ad4.w;
    float den_h = (h == 0) ? d0   : (h == 1) ? d1   : (h == 2) ? d2   : d3;

    float acc[8] = {0,0,0,0,0,0,0,0};
    const float* Hc = H + cl * 8;
    int i = start + eg;
    for (; i + 4 < end; i += 8){
        int sA = csr_src[i];
        int sB = csr_src[i + 4];
        float eA = als[(size_t)sA * 4 + h] + ad_h; eA = eA > 0.f ? eA : 0.2f * eA;
        float eB = als[(size_t)sB * 4 + h] + ad_h; eB = eB > 0.f ? eB : 0.2f * eB;
        float wA = __expf(eA - m_h);
        float wB = __expf(eB - m_h);
        const float* pA = Hc + (size_t)sA * 128;
        const float* pB = Hc + (size_t)sB * 128;
        float4 a0 = *(const float4*)pA;
        float4 a1 = *(const float4*)(pA + 4);
        float4 b0 = *(const float4*)pB;
        float4 b1 = *(const float4*)(pB + 4);
        acc[0] += wA * a0.x + wB * b0.x; acc[1] += wA * a0.y + wB * b0.y;
        acc[2] += wA * a0.z + wB * b0.z; acc[3] += wA * a0.w + wB * b0.w;
        acc[4] += wA * a1.x + wB * b1.x; acc[5] += wA * a1.y + wB * b1.y;
        acc[6] += wA * a1.z + wB * b1.z; acc[7] += wA * a1.w + wB * b1.w;
    }
    if (i < end){
        int s = csr_src[i];
        float e = als[(size_t)s * 4 + h] + ad_h; e = e > 0.f ? e : 0.2f * e;
        float w = __expf(e - m_h);
        const float* p = Hc + (size_t)s * 128;
        float4 a0 = *(const float4*)p;
        float4 a1 = *(const float4*)(p + 4);
        acc[0] += w * a0.x; acc[1] += w * a0.y; acc[2] += w * a0.z; acc[3] += w * a0.w;
        acc[4] += w * a1.x; acc[5] += w * a1.y; acc[6] += w * a1.z; acc[7] += w * a1.w;
    }
    #pragma unroll
    for (int j = 0; j < 8; ++j){
        acc[j] += __shfl_xor(acc[j], 16);
        acc[j] += __shfl_xor(acc[j], 32);
    }

    if (eg == 0){
        float inv = 1.f / (den_h + 1e-16f);
        int col = cl * 8;
        float4 bv0 = *(const float4*)(bias + col);
        float4 bv1 = *(const float4*)(bias + col + 4);
        float v[8];
        v[0] = acc[0]*inv + bv0.x; v[1] = acc[1]*inv + bv0.y;
        v[2] = acc[2]*inv + bv0.z; v[3] = acc[3]*inv + bv0.w;
        v[4] = acc[4]*inv + bv1.x; v[5] = acc[5]*inv + bv1.y;
        v[6] = acc[6]*inv + bv1.z; v[7] = acc[7]*inv + bv1.w;
        if (do_elu){
            #pragma unroll
            for (int j = 0; j < 8; ++j) v[j] = v[j] > 0.f ? v[j] : __expf(v[j]) - 1.f;
        }
        float4 o0 = {v[0], v[1], v[2], v[3]};
        float4 o1 = {v[4], v[5], v[6], v[7]};
        *(float4*)&out[(size_t)node * 128 + col]     = o0;
        *(float4*)&out[(size_t)node * 128 + col + 4] = o1;
    }
}

// ---------------- layer 4: [n,128] x [128,16], heads=1 ----------------

__global__ __launch_bounds__(256) void gemm16_kernel(const float* __restrict__ X,
                                                     const float* __restrict__ W,
                                                     float* __restrict__ H4, int n){
    __shared__ float Ws[128 * 16];
    int tid = threadIdx.x;
    for (int i = tid; i < 2048; i += 256) Ws[i] = W[i];
    __syncthreads();
    int gid = blockIdx.x * 256 + tid;
    if (gid >= n * 16) return;
    int j = gid & 15, node = gid >> 4;
    const float4* xr = (const float4*)(X + (size_t)node * 128);
    float s = 0.f;
    #pragma unroll 8
    for (int k4 = 0; k4 < 32; ++k4){
        float4 xv = xr[k4];
        s += xv.x * Ws[(k4*4+0)*16 + j] + xv.y * Ws[(k4*4+1)*16 + j]
           + xv.z * Ws[(k4*4+2)*16 + j] + xv.w * Ws[(k4*4+3)*16 + j];
    }
    H4[gid] = s;
}

__global__ __launch_bounds__(256) void al16_kernel(const float* __restrict__ H4,
                                                   const float* __restrict__ as2,
                                                   const float* __restrict__ ad2,
                                                   float* __restrict__ als4,
                                                   float* __restrict__ ald4, int n){
    int node = blockIdx.x * 256 + threadIdx.x;
    if (node >= n) return;
    const float4* hr = (const float4*)(H4 + (size_t)node * 16);
    const float4* asr = (const float4*)as2;
    const float4* adr = (const float4*)ad2;
    float ss = 0.f, sd = 0.f;
    #pragma unroll
    for (int i = 0; i < 4; ++i){
        float4 hv = hr[i], av = asr[i], dv = adr[i];
        ss += hv.x*av.x + hv.y*av.y + hv.z*av.z + hv.w*av.w;
        sd += hv.x*dv.x + hv.y*dv.y + hv.z*dv.z + hv.w*dv.w;
    }
    als4[node] = ss; ald4[node] = sd;
}

// ---------------- aggregation (16 ch, 1 head): one wave per node ----------------
// pass1/2 lane-parallel; pass3: 16 edge-groups x 4 ch-lanes (float4 each)

__global__ __launch_bounds__(256) void aggregate16_kernel(const float* __restrict__ H4,
                                                          const float* __restrict__ als4,
                                                          const float* __restrict__ ald4,
                                                          const int* __restrict__ rowptr,
                                                          const int* __restrict__ csr_src,
                                                          const float* __restrict__ bias,
                                                          float* __restrict__ out, int n){
    int node = blockIdx.x * 4 + (threadIdx.x >> 6);
    int lane = threadIdx.x & 63;
    if (node >= n) return;
    int start = rowptr[node], end = rowptr[node + 1];
    float adn = ald4[node];

    float m = -1e30f;
    for (int i = start + lane; i < end; i += 64){
        int s = csr_src[i];
        float e = als4[s] + adn; e = e > 0.f ? e : 0.2f * e;
        m = fmaxf(m, e);
    }
    #pragma unroll
    for (int off = 32; off > 0; off >>= 1) m = fmaxf(m, __shfl_xor(m, off));

    float den = 0.f;
    for (int i = start + lane; i < end; i += 64){
        int s = csr_src[i];
        float e = als4[s] + adn; e = e > 0.f ? e : 0.2f * e;
        den += __expf(e - m);
    }
    #pragma unroll
    for (int off = 32; off > 0; off >>= 1) den += __shfl_xor(den, off);

    int eg = lane >> 2, cl = lane & 3;
    float acc0 = 0.f, acc1 = 0.f, acc2 = 0.f, acc3 = 0.f;
    for (int i = start + eg; i < end; i += 16){
        int s = csr_src[i];
        float e = als4[s] + adn; e = e > 0.f ? e : 0.2f * e;
        float w = __expf(e - m);
        float4 hv = *(const float4*)(H4 + (size_t)s * 16 + cl * 4);
        acc0 += w * hv.x; acc1 += w * hv.y; acc2 += w * hv.z; acc3 += w * hv.w;
    }
    #pragma unroll
    for (int off = 4; off <= 32; off <<= 1){
        acc0 += __shfl_xor(acc0, off); acc1 += __shfl_xor(acc1, off);
        acc2 += __shfl_xor(acc2, off); acc3 += __shfl_xor(acc3, off);
    }

    if (eg == 0){
        float inv = 1.f / (den + 1e-16f);
        float4 bv = *(const float4*)(bias + cl * 4);
        float4 o = {acc0*inv + bv.x, acc1*inv + bv.y, acc2*inv + bv.z, acc3*inv + bv.w};
        *(float4*)&out[(size_t)node * 16 + cl * 4] = o;
    }
}

// ---------------- launcher ----------------

extern "C" void kernel_launch(void* const* d_in, const int* in_sizes, int n_in,
                              void* d_out, int out_size, void* d_ws, size_t ws_size,
                              hipStream_t stream) {
    const float* x   = (const float*)d_in[0];
    const int*   ei  = (const int*)d_in[1];
    const float* W1  = (const float*)d_in[3];
    const float* as1 = (const float*)d_in[4];
    const float* ad1 = (const float*)d_in[5];
    const float* b1  = (const float*)d_in[6];
    const float* Wh  = (const float*)d_in[7];
    const float* ash = (const float*)d_in[8];
    const float* adh = (const float*)d_in[9];
    const float* bh  = (const float*)d_in[10];
    const float* W2  = (const float*)d_in[11];
    const float* as2 = (const float*)d_in[12];
    const float* ad2 = (const float*)d_in[13];
    const float* b2  = (const float*)d_in[14];

    int N = in_sizes[0] / 128;
    int E = in_sizes[1] / 2;
    int Et = E + N;
    const int* srcA = ei;
    const int* dstA = ei + E;

    char* ws = (char*)d_ws;
    size_t off = 0;
    auto alloc = [&](size_t bytes) -> void* {
        void* p = ws + off;
        off = (off + bytes + 255) & ~(size_t)255;
        return p;
    };
    int* degcur  = (int*)alloc((size_t)2 * N * 4);
    int* deg     = degcur;
    int* cursor  = degcur + N;
    int* rowptr  = (int*)alloc((size_t)(N + 1) * 4);
    int* csr_src = (int*)alloc((size_t)Et * 4);
    float* xbuf  = (float*)alloc((size_t)N * 128 * 4);
    float* hfeat = (float*)alloc((size_t)N * 128 * 4);
    float* als   = (float*)alloc((size_t)N * 4 * 4);
    float* ald   = (float*)alloc((size_t)N * 4 * 4);
    float* h4    = (float*)alloc((size_t)N * 16 * 4);
    float* als4  = (float*)alloc((size_t)N * 4);
    float* ald4  = (float*)alloc((size_t)N * 4);

    hipMemsetAsync(degcur, 0, (size_t)2 * N * 4, stream);
    count_deg_kernel<<<divup(Et, 256), 256, 0, stream>>>(dstA, deg, E, Et);
    scan_kernel<<<1, 1024, 0, stream>>>(deg, rowptr, N, Et);
    fill_csr_kernel<<<divup(Et, 256), 256, 0, stream>>>(srcA, dstA, rowptr, cursor, csr_src, E, Et);

    float* out = (float*)d_out;

    // layer 1
    gemm128_kernel<<<divup(N, 32), 256, 0, stream>>>(x, W1, hfeat, N);
    al128_kernel<<<divup(N * 4, 256), 256, 0, stream>>>(hfeat, as1, ad1, als, ald, N);
    aggregate128_kernel<<<divup(N, 4), 256, 0, stream>>>(hfeat, als, ald, rowptr, csr_src, b1, xbuf, N, 1);

    // hidden layers 2,3
    for (int l = 0; l < 2; ++l){
        gemm128_kernel<<<divup(N, 32), 256, 0, stream>>>(xbuf, Wh + (size_t)l * 128 * 128, hfeat, N);
        al128_kernel<<<divup(N * 4, 256), 256, 0, stream>>>(hfeat, ash + l * 128, adh + l * 128, als, ald, N);
        aggregate128_kernel<<<divup(N, 4), 256, 0, stream>>>(hfeat, als, ald, rowptr, csr_src, bh + l * 128, xbuf, N, 1);
    }

    // layer 4 (heads=1, 16 out)
    gemm16_kernel<<<divup(N * 16, 256), 256, 0, stream>>>(xbuf, W2, h4, N);
    al16_kernel<<<divup(N, 256), 256, 0, stream>>>(h4, as2, ad2, als4, ald4, N);
    aggregate16_kernel<<<divup(N, 4), 256, 0, stream>>>(h4, als4, ald4, rowptr, csr_src, b2, out, N);
}